// Round 9
// baseline (72.681 us; speedup 1.0000x reference)
//
#include <hip/hip_runtime.h>
#include <math.h>

#define KPTS 512
#define VOX (64*64*64)
#define NBLK 4096            // 16x16x16 NMS blocks per instance, 1 slot each
#define OVF 1024             // overflow (tie) slots per instance
#define NSEL 1024
#define GRID 512

typedef unsigned long long u64;
typedef unsigned int u32;

typedef float f2v __attribute__((ext_vector_type(2)));
typedef f2v f2a __attribute__((aligned(4)));   // 8B vector load at 4B alignment

// ---- agent-scope coherent (LLC-coherent, XCD-safe) accessors ----
__device__ __forceinline__ void cst64(u64* p, u64 v) {
  __hip_atomic_store(p, v, __ATOMIC_RELAXED, __HIP_MEMORY_SCOPE_AGENT);
}
__device__ __forceinline__ u64 cld64(const u64* p) {
  return __hip_atomic_load(p, __ATOMIC_RELAXED, __HIP_MEMORY_SCOPE_AGENT);
}
__device__ __forceinline__ void cst32(u32* p, u32 v) {
  __hip_atomic_store(p, v, __ATOMIC_RELAXED, __HIP_MEMORY_SCOPE_AGENT);
}
__device__ __forceinline__ u32 cld32(const u32* p) {
  return __hip_atomic_load(p, __ATOMIC_RELAXED, __HIP_MEMORY_SCOPE_AGENT);
}
__device__ __forceinline__ u32 cadd32(u32* p, u32 v) {
  return __hip_atomic_fetch_add(p, v, __ATOMIC_RELAXED, __HIP_MEMORY_SCOPE_AGENT);
}
__device__ __forceinline__ void cstf(float* p, float v) { cst32((u32*)p, __float_as_uint(v)); }
__device__ __forceinline__ float cldf(const float* p) { return __uint_as_float(cld32((const u32*)p)); }

// f32 op-sequence sigmoid with correctly-rounded expf (via double):
// t = rn(exp(-x)); s = 1/(1+t)  -- mimics NumPy f32 semantics.
__device__ __forceinline__ float ref_sigmoid(float x) {
  float t = (float)exp(-(double)x);
  float d = 1.0f + t;
  return 1.0f / d;
}

// bar layout (u32 words, lines of 16 words = 64B; memset 0 each replay):
//   arrive[inst][l] @ (inst*8+l)*16        l<8, target 16 blocks each
//   done  [inst][l] @ (32+inst*8+l)*16     l<8, target 16 blocks each
//   ovfCnt[inst]    @ (64+inst)*16
__device__ __forceinline__ int key_bin(u64 key) {
  u32 vb = (u32)(key >> 32);
  return (vb >= 0x3F800000u) ? 255 : ((vb < 0x3F000000u) ? 0 : (int)((vb >> 15) & 0xFF));
}

__device__ __forceinline__ void emit_pt(int inst, u64 key, u32 rank,
                                        u32* __restrict__ pts,
                                        float* __restrict__ out) {
  u32 idx = ~(u32)key;                    // 0xFFFFFFFF - low
  cst32(pts + inst * KPTS + rank, idx + 1u);   // +1: 0 is the spin sentinel
  int x = idx & 63, y = (idx >> 6) & 63, z = (int)(idx >> 12);
  float gx = ((float)x * 2.0f) / 63.0f - 1.0f;
  float gy = ((float)y * 2.0f) / 63.0f - 1.0f;
  float gz = ((float)z * 2.0f) / 63.0f - 1.0f;
  int m = inst >> 1, b = inst & 1;
  float* g = out + (size_t)m * 3072 + (size_t)(b * KPTS + rank) * 3;
  g[0] = gx; g[1] = gy; g[2] = gz;        // out: host-read only, plain stores
}

// Whole pipeline, ZERO grid barriers: per-instance dataflow only.
// Block bid owns: NMS strips {2bid, 2bid+1} (instance bid>>7),
// topk for instance bid (bid<4), sampling points [4bid,4bid+4) of
// instance bid>>7, matcher tile bid&255 of batch bid>>8.
__global__ void __launch_bounds__(256, 2) fused_all(
    const float* __restrict__ k1, const float* __restrict__ k2,
    const float* __restrict__ f1, const float* __restrict__ f2,
    const float* __restrict__ fc_w, const float* __restrict__ fc_b,
    float* __restrict__ out, u64* __restrict__ cands, u64* __restrict__ ovf,
    u32* __restrict__ pts, float* __restrict__ norms, float* __restrict__ desc,
    u32* __restrict__ bar)
{
  __shared__ __align__(16) char smem[26624];
  int bid = blockIdx.x, tid = threadIdx.x;

  // ===== stage 1: sigmoid + 4x4x4 NMS; both strips belong to inst bid>>7 =====
  {
    float (*sm)[16] = (float (*)[16])smem;        // 256B
    u32* wcnt = (u32*)(smem + 256);               // 64B
    #pragma unroll
    for (int it = 0; it < 2; it++) {
      int u = bid * 2 + it;
      int strip = u & 255, inst = u >> 8;
      const float* vol = ((inst >> 1) ? k2 : k1) + (size_t)(inst & 1) * VOX;
      __syncthreads();                            // LDS reuse across iters
      if (tid < 16) wcnt[tid] = 0;
      int x = tid & 63, yl = tid >> 6;
      int yb = strip & 15, zb = strip >> 4;
      int y = yb * 4 + yl, z0 = zb * 4;
      float s[4];
      #pragma unroll
      for (int zl = 0; zl < 4; zl++)
        s[zl] = ref_sigmoid(vol[((z0 + zl) << 12) | (y << 6) | x]);
      float m = fmaxf(fmaxf(s[0], s[1]), fmaxf(s[2], s[3]));
      m = fmaxf(m, __shfl_xor(m, 1));
      m = fmaxf(m, __shfl_xor(m, 2));             // max over 4x * 1y * 4z
      if ((x & 3) == 0) sm[yl][x >> 2] = m;
      __syncthreads();
      int xb = x >> 2;
      float bm = fmaxf(fmaxf(sm[0][xb], sm[1][xb]), fmaxf(sm[2][xb], sm[3][xb]));
      int nb = ((zb * 16 + yb) << 4) | xb;
      #pragma unroll
      for (int zl = 0; zl < 4; zl++) {
        if (s[zl] == bm) {                        // winner (all ties emitted)
          int addr = ((z0 + zl) << 12) | (y << 6) | x;
          u64 key = ((u64)__float_as_uint(s[zl]) << 32) | (u64)(0xFFFFFFFFu - (u32)addr);
          u32 r = atomicAdd(&wcnt[xb], 1u);       // LDS atomic, ~1/block
          if (r == 0) {                           // slot occupant (set-determinism)
            cst64(&cands[(size_t)inst * NBLK + nb], key);
          } else {                                // rare tie -> global overflow
            u32 p = cadd32(bar + (64 + inst) * 16, 1u);
            if (p < OVF) cst64(&ovf[(size_t)inst * OVF + p], key);
          }
        }
      }
    }
    __syncthreads();   // drains ALL waves' cands/ovf stores (vmcnt before s_barrier)
    if (tid == 0)
      cadd32(bar + ((bid >> 7) * 8 + (bid & 7)) * 16, 1u);   // arrive[inst] += 1
  }

  // ===== stage 2: per-instance top-512 (spin on arrive, then prune+rank) =====
  if (bid < 4) {
    int inst = bid;
    if (tid == 0) {                               // wait all 128 inst blocks
      u32 s;
      do {
        s = 0;
        #pragma unroll
        for (int l = 0; l < 8; l++) s += cld32(bar + (inst * 8 + l) * 16);
        if (s < 128u) __builtin_amdgcn_s_sleep(4);
      } while (s < 128u);
    }
    __syncthreads();
    u64* sel    = (u64*)smem;                     // 8192B
    u32* hist   = (u32*)(smem + 8192);            // 1024B
    u32* selCnt = (u32*)(smem + 9216);
    int* bstar  = (int*)(smem + 9220);
    hist[tid] = 0;
    if (tid == 0) *selCnt = 0;
    __syncthreads();
    const u64* cb = cands + (size_t)inst * NBLK;  // all 4096 valid
    const u64* ob = ovf + (size_t)inst * OVF;
    u32 ov = cld32(bar + (64 + inst) * 16); if (ov > OVF) ov = OVF;
    for (int g = 0; g < 2; g++) {                 // pass 1: histogram
      u64 k8[8];
      #pragma unroll
      for (int q = 0; q < 8; q++) k8[q] = cld64(cb + tid + (g * 8 + q) * 256);
      #pragma unroll
      for (int q = 0; q < 8; q++) atomicAdd(&hist[key_bin(k8[q])], 1u);
    }
    for (u32 i = tid; i < ov; i += 256) atomicAdd(&hist[key_bin(cld64(ob + i))], 1u);
    __syncthreads();
    if (tid == 0) {
      u32 cum = 0; int b = 255;
      for (; b >= 0; b--) { cum += hist[b]; if (cum >= KPTS) break; }
      *bstar = (b < 0) ? 0 : b;
    }
    __syncthreads();
    int B = *bstar;
    for (int g = 0; g < 2; g++) {                 // pass 2: append survivors
      u64 k8[8];
      #pragma unroll
      for (int q = 0; q < 8; q++) k8[q] = cld64(cb + tid + (g * 8 + q) * 256);
      #pragma unroll
      for (int q = 0; q < 8; q++) {
        if (key_bin(k8[q]) >= B) {
          u32 p = atomicAdd(selCnt, 1u);
          if (p < NSEL) sel[p] = k8[q];
        }
      }
    }
    for (u32 i = tid; i < ov; i += 256) {
      u64 key = cld64(ob + i);
      if (key_bin(key) >= B) {
        u32 p = atomicAdd(selCnt, 1u);
        if (p < NSEL) sel[p] = key;
      }
    }
    __syncthreads();
    u32 sc = *selCnt; if (sc > NSEL) sc = NSEL;
    // rank by broadcast scan: (value desc, idx asc) == u64 desc; keys unique;
    // rank independent of sel[] order -> deterministic output.
    u64 m0 = (tid < sc) ? sel[tid] : 0ull;
    u64 m1 = (tid + 256 < sc) ? sel[tid + 256] : 0ull;
    u64 m2 = (tid + 512 < sc) ? sel[tid + 512] : 0ull;
    u64 m3 = (tid + 768 < sc) ? sel[tid + 768] : 0ull;
    u32 r0 = 0, r1 = 0, r2 = 0, r3 = 0;
    for (u32 i = 0; i < sc; i++) {
      u64 v = sel[i];                             // LDS broadcast (same addr)
      r0 += (v > m0); r1 += (v > m1); r2 += (v > m2); r3 += (v > m3);
    }
    if (tid < sc && r0 < KPTS) emit_pt(inst, m0, r0, pts, out);
    if (tid + 256 < sc && r1 < KPTS) emit_pt(inst, m1, r1, pts, out);
    if (tid + 512 < sc && r2 < KPTS) emit_pt(inst, m2, r2, pts, out);
    if (tid + 768 < sc && r3 < KPTS) emit_pt(inst, m3, r3, pts, out);
  }

  // ===== stage 3: trilinear sampling; spin on own pts dword (dataflow) =====
  {
    int w = bid * 4 + (tid >> 6);                 // 0..2047
    int inst = w >> 9, kp = w & 511;              // inst == bid>>7
    int m = inst >> 1, b = inst & 1;
    int lane = tid & 63;                          // channel 0..63
    const u32* pp = pts + inst * KPTS + kp;
    u32 v;
    while ((v = cld32(pp)) == 0u) __builtin_amdgcn_s_sleep(2);
    int idx = (int)(v - 1u);
    int x = idx & 63, y = (idx >> 6) & 63, z = idx >> 12;
    float gx = ((float)x * 2.0f) / 63.0f - 1.0f;
    float gy = ((float)y * 2.0f) / 63.0f - 1.0f;
    float gz = ((float)z * 2.0f) / 63.0f - 1.0f;
    float ix = ((gx + 1.0f) * 64.0f - 1.0f) * 0.5f;
    float iy = ((gy + 1.0f) * 64.0f - 1.0f) * 0.5f;
    float iz = ((gz + 1.0f) * 64.0f - 1.0f) * 0.5f;
    float x0f = floorf(ix), y0f = floorf(iy), z0f = floorf(iz);
    float fx = ix - x0f, fy = iy - y0f, fz = iz - z0f;
    int x0 = (int)x0f, y0 = (int)y0f, z0 = (int)z0f;
    int xc = x0 < 0 ? 0 : (x0 > 62 ? 62 : x0);
    bool xlo = (x0 == xc);
    float wx0 = (x0 >= 0) ? (1.0f - fx) : 0.0f;
    float wx1 = (x0 <= 62) ? fx : 0.0f;
    int yc0 = y0 < 0 ? 0 : y0, yc1 = (y0 + 1) > 63 ? 63 : (y0 + 1);
    int zc0 = z0 < 0 ? 0 : z0, zc1 = (z0 + 1) > 63 ? 63 : (z0 + 1);
    float wy0 = (y0 >= 0) ? (1.0f - fy) : 0.0f;
    float wy1 = ((y0 + 1) <= 63) ? fy : 0.0f;
    float wz0 = (z0 >= 0) ? (1.0f - fz) : 0.0f;
    float wz1 = ((z0 + 1) <= 63) ? fz : 0.0f;

    const float* fv = (m ? f2 : f1) + ((size_t)b * 64 + lane) * VOX;
    float acc = 0.0f;
    #pragma unroll
    for (int dz = 0; dz < 2; dz++) {
      int zz = dz ? zc1 : zc0; float wzz = dz ? wz1 : wz0;
      #pragma unroll
      for (int dy = 0; dy < 2; dy++) {
        int yy = dy ? yc1 : yc0; float wyy = dy ? wy1 : wy0;
        f2a vv = *reinterpret_cast<const f2a*>(fv + ((zz << 12) | (yy << 6) | xc));
        float v0 = xlo ? vv.x : vv.y;
        float v1 = xlo ? vv.y : vv.x;
        acc = fmaf(wzz * wyy, fmaf(v0, wx0, v1 * wx1), acc);
      }
    }
    cstf(&desc[((size_t)inst * KPTS + kp) * 64 + lane], acc);  // coalesced
    float ss = acc * acc;
    #pragma unroll
    for (int o = 32; o; o >>= 1) ss += __shfl_xor(ss, o);
    const float* kv = (m ? k2 : k1) + (size_t)b * VOX;
    float part = 0.0f;
    if (lane < 4) {
      int dz = lane >> 1, dy = lane & 1;
      int zz = dz ? zc1 : zc0; float wzz = dz ? wz1 : wz0;
      int yy = dy ? yc1 : yc0; float wyy = dy ? wy1 : wy0;
      f2a vv = *reinterpret_cast<const f2a*>(kv + ((zz << 12) | (yy << 6) | xc));
      float v0 = xlo ? vv.x : vv.y;
      float v1 = xlo ? vv.y : vv.x;
      part = wzz * wyy * fmaf(v0, wx0, v1 * wx1);
    }
    part += __shfl_xor(part, 1);
    part += __shfl_xor(part, 2);
    if (lane == 0) {
      cstf(&norms[inst * KPTS + kp], sqrtf(ss));
      out[6144 + m * 1024 + b * KPTS + kp] = part;
    }
    __syncthreads();   // drains all 4 waves' desc/norms stores
    if (tid == 0)
      cadd32(bar + (32 + inst * 8 + (bid & 7)) * 16, 1u);    // done[inst] += 1
  }

  // ===== stage 4: matcher; spin on done[b] & done[2+b], then one tile =====
  {
    int b = bid >> 8, ti = (bid >> 4) & 15, tj = bid & 15;
    if (tid == 0) {                               // wait both source insts
      u32 s;
      do {
        s = 0;
        #pragma unroll
        for (int l = 0; l < 8; l++) {
          s += cld32(bar + (32 + b * 8 + l) * 16);
          s += cld32(bar + (32 + (2 + b) * 8 + l) * 16);
        }
        if (s < 256u) __builtin_amdgcn_s_sleep(4);
      } while (s < 256u);
    }
    __syncthreads();                              // also fences LDS arena reuse
    float (*e0t)[68] = (float (*)[68])smem;             // 8704B
    float (*e1t)[68] = (float (*)[68])(smem + 8704);    // 8704B
    float (*d2t)[68] = (float (*)[68])(smem + 17408);   // 8704B
    float* n1s = (float*)(smem + 26112);                // 128B
    float* n2s = (float*)(smem + 26240);                // 128B
    int i0 = ti * 32, j0 = tj * 32;
    const float* d1 = desc + (size_t)b * KPTS * 64;
    const float* d2 = desc + (size_t)(2 + b) * KPTS * 64;
    {
      int row = tid >> 3, ci = (tid & 7) * 8;
      const u64* p1 = (const u64*)(d1 + (size_t)(i0 + row) * 64 + ci);
      const u64* p2 = (const u64*)(d2 + (size_t)(j0 + row) * 64 + ci);
      float a[8], c[8];
      #pragma unroll
      for (int q = 0; q < 4; q++) {
        u64 v = cld64(p1 + q);
        a[2 * q]     = __uint_as_float((u32)v);
        a[2 * q + 1] = __uint_as_float((u32)(v >> 32));
        u64 w = cld64(p2 + q);
        c[2 * q]     = __uint_as_float((u32)w);
        c[2 * q + 1] = __uint_as_float((u32)(w >> 32));
      }
      #pragma unroll
      for (int k = 0; k < 8; k++) {
        float w0 = fc_w[ci + k], w1 = fc_w[64 + ci + k];  // read-only input
        e0t[row][ci + k] = a[k] * w0;
        e1t[row][ci + k] = a[k] * w1;
        d2t[row][ci + k] = c[k];
      }
    }
    if (tid < 32) n1s[tid] = cldf(&norms[b * KPTS + i0 + tid]);
    else if (tid < 64) n2s[tid - 32] = cldf(&norms[(2 + b) * KPTS + j0 + (tid - 32)]);
    __syncthreads();
    int j = tid & 31, r0w = tid >> 5;
    float bb0 = fc_b[0], bb1 = fc_b[1];
    float s0a[4] = {0, 0, 0, 0}, s1a[4] = {0, 0, 0, 0};
    #pragma unroll
    for (int q = 0; q < 16; q++) {
      float4 D = *(const float4*)&d2t[j][q * 4];
      #pragma unroll
      for (int r = 0; r < 4; r++) {
        int i = r0w + r * 8;
        float4 E0 = *(const float4*)&e0t[i][q * 4];
        float4 E1 = *(const float4*)&e1t[i][q * 4];
        s0a[r] = fmaf(E0.x, D.x, s0a[r]); s0a[r] = fmaf(E0.y, D.y, s0a[r]);
        s0a[r] = fmaf(E0.z, D.z, s0a[r]); s0a[r] = fmaf(E0.w, D.w, s0a[r]);
        s1a[r] = fmaf(E1.x, D.x, s1a[r]); s1a[r] = fmaf(E1.y, D.y, s1a[r]);
        s1a[r] = fmaf(E1.z, D.z, s1a[r]); s1a[r] = fmaf(E1.w, D.w, s1a[r]);
      }
    }
    float n2 = n2s[j];
    #pragma unroll
    for (int r = 0; r < 4; r++) {
      int i = r0w + r * 8;
      int gi = i0 + i, gj = j0 + j;
      size_t row = ((size_t)(b * KPTS + gi)) * KPTS + gj;
      *(float2*)(out + 8192 + row * 2) = make_float2(s0a[r] + bb0, s1a[r] + bb1);
      float n1 = n1s[i];
      out[1056768 + row] = n1 * fabsf(1.0f / (1e-6f + n1) - 1.0f / (1e-6f + n2));
    }
  }
}

extern "C" void kernel_launch(void* const* d_in, const int* in_sizes, int n_in,
                              void* d_out, int out_size, void* d_ws, size_t ws_size,
                              hipStream_t stream) {
  const float* k1 = (const float*)d_in[0];
  const float* k2 = (const float*)d_in[1];
  const float* f1 = (const float*)d_in[2];
  const float* f2 = (const float*)d_in[3];
  const float* fw = (const float*)d_in[4];
  const float* fb = (const float*)d_in[5];
  float* out = (float*)d_out;
  char* ws = (char*)d_ws;
  // ws: [bar 8KB | pts 8KB] (memset 0 each replay) | cands 128KB | ovf 32KB
  //     | norms 8KB | desc 512KB
  u32* bar     = (u32*)ws;
  u32* pts     = (u32*)(ws + 8192);
  u64* cands   = (u64*)(ws + 16384);
  u64* ovf     = (u64*)(ws + 16384 + 131072);
  float* norms = (float*)(ws + 180224);
  float* desc  = (float*)(ws + 188416);

  hipMemsetAsync(ws, 0, 16384, stream);   // arrival/done/ovf counters + pts sentinels

  void* args[] = { (void*)&k1, (void*)&k2, (void*)&f1, (void*)&f2,
                   (void*)&fw, (void*)&fb, (void*)&out,
                   (void*)&cands, (void*)&ovf, (void*)&pts,
                   (void*)&norms, (void*)&desc, (void*)&bar };
  hipLaunchCooperativeKernel((const void*)fused_all, dim3(GRID), dim3(256),
                             args, 0, stream);
}